// Round 14
// baseline (349.067 us; speedup 1.0000x reference)
//
#include <hip/hip_runtime.h>
#include <hip/hip_cooperative_groups.h>
#include <stdint.h>

// ---------------------------------------------------------------------------
// WideAndDeep: B=16384, F=3, C=256, D=64, H=1024, ND=13
// Primary: ONE cooperative dispatch, 256 blocks x 512 threads (1 block/CU
// guaranteed co-residency), phases: prep -> GEMM1 -> GEMM2+W3 -> sigmoid,
// grid.sync() between phases. Each GEMM phase: 2 sequential 128x256 tiles.
// Fallback (if hipLaunchCooperativeKernel errors, e.g. TooLarge/capture-
// unsupported): the proven R12 4-kernel pipeline. Both paths compute
// identical results.
// GEMM core: 128x256 tile, 8 waves 2m x 4n, wave tile 64x64, 16x16x32 MFMA,
// BK=32 dbuf LDS, global_load_lds(16B), permuted B-cols (frag j = col 4rl+j).
// ---------------------------------------------------------------------------

#define BATCH 16384
#define HDIM 1024
#define K1 224
#define DEEP_IN 205

typedef short bf16x8 __attribute__((ext_vector_type(8)));
typedef float f32x4 __attribute__((ext_vector_type(4)));
typedef uint16_t u16x8 __attribute__((ext_vector_type(8)));
typedef uint16_t u16x4 __attribute__((ext_vector_type(4)));

__device__ __forceinline__ uint16_t f2bf(float f) {
    uint32_t x;
    __builtin_memcpy(&x, &f, 4);
    uint32_t r = (x + 0x7fffu + ((x >> 16) & 1u)) >> 16;
    return (uint16_t)r;
}

__device__ __forceinline__ void async_ld16(const uint16_t* g, uint16_t* l) {
    __builtin_amdgcn_global_load_lds(
        (const __attribute__((address_space(1))) uint32_t*)g,
        (__attribute__((address_space(3))) uint32_t*)l, 16, 0, 0);
}

// GEMM core (R12, permuted B columns). Needs in scope: tid, M, and
// __shared__ Al[2][4096], Bl[2][8192]. ID_ = tile index in [0, (M/128)*4).
#define GEMM_CORE(A_, B_, K_, ID_)                                             \
    const int lane = tid & 63;                                                 \
    const int wave = tid >> 6;                                                 \
    const int wm = wave >> 2;                                                  \
    const int wn = wave & 3;                                                   \
    const int xcd = (ID_) & 7;                                                 \
    const int slot = (ID_) >> 3;                                               \
    const int mbX = (M >> 7) >> 3;                                             \
    const int by = xcd * mbX + (slot >> 2);                                    \
    const int bx = slot & 3;                                                   \
    const int bm = by * 128;                                                   \
    const int bn = bx * 256;                                                   \
    const int rl = lane & 15, q = lane >> 4;                                   \
    f32x4 acc[4][4];                                                           \
    _Pragma("unroll") for (int i = 0; i < 4; i++)                              \
        _Pragma("unroll") for (int j = 0; j < 4; j++) acc[i][j] = (f32x4)0.f;  \
    const int cc0 = 2 * wave, cc1 = 2 * wave + 1;                              \
    const uint16_t* aS = A_ + (size_t)(bm + wave * 16 + rl) * K_ + q * 8;      \
    const uint16_t* bS0 = B_ + (size_t)(bn + (cc0 >> 2) * 64 + 4 * rl + (cc0 & 3)) * K_ + q * 8; \
    const uint16_t* bS1 = B_ + (size_t)(bn + (cc1 >> 2) * 64 + 4 * rl + (cc1 & 3)) * K_ + q * 8; \
    const int dA = wave * 512, dB0 = cc0 * 512, dB1 = cc1 * 512;               \
    async_ld16(aS, &Al[0][dA]);                                                \
    async_ld16(bS0, &Bl[0][dB0]);                                              \
    async_ld16(bS1, &Bl[0][dB1]);                                              \
    asm volatile("s_waitcnt vmcnt(0)" ::: "memory");                           \
    __syncthreads();                                                           \
    int p = 0;                                                                 \
    for (int k0 = 32; k0 < K_; k0 += 32) {                                     \
        async_ld16(aS + k0, &Al[p ^ 1][dA]);                                   \
        async_ld16(bS0 + k0, &Bl[p ^ 1][dB0]);                                 \
        async_ld16(bS1 + k0, &Bl[p ^ 1][dB1]);                                 \
        bf16x8 af[4], bfr[4];                                                  \
        _Pragma("unroll") for (int i = 0; i < 4; i++)                          \
            af[i] = *(const bf16x8*)&Al[p][(wm * 4 + i) * 512 + lane * 8];     \
        _Pragma("unroll") for (int j = 0; j < 4; j++)                          \
            bfr[j] = *(const bf16x8*)&Bl[p][(wn * 4 + j) * 512 + lane * 8];    \
        _Pragma("unroll") for (int i = 0; i < 4; i++)                          \
            _Pragma("unroll") for (int j = 0; j < 4; j++)                      \
                acc[i][j] = __builtin_amdgcn_mfma_f32_16x16x32_bf16(           \
                    af[i], bfr[j], acc[i][j], 0, 0, 0);                        \
        asm volatile("s_waitcnt vmcnt(0)" ::: "memory");                       \
        __syncthreads();                                                       \
        p ^= 1;                                                                \
    }                                                                          \
    {                                                                          \
        bf16x8 af[4], bfr[4];                                                  \
        _Pragma("unroll") for (int i = 0; i < 4; i++)                          \
            af[i] = *(const bf16x8*)&Al[p][(wm * 4 + i) * 512 + lane * 8];     \
        _Pragma("unroll") for (int j = 0; j < 4; j++)                          \
            bfr[j] = *(const bf16x8*)&Bl[p][(wn * 4 + j) * 512 + lane * 8];    \
        _Pragma("unroll") for (int i = 0; i < 4; i++)                          \
            _Pragma("unroll") for (int j = 0; j < 4; j++)                      \
                acc[i][j] = __builtin_amdgcn_mfma_f32_16x16x32_bf16(           \
                    af[i], bfr[j], acc[i][j], 0, 0, 0);                        \
    }

// ===========================================================================
// Cooperative mega-kernel: 256 blocks x 512 threads.
// ===========================================================================
__global__ __launch_bounds__(512, 4) void wad_mega(
    const int* __restrict__ sp, const float* __restrict__ dense,
    const float* __restrict__ emb, const float* __restrict__ W1,
    const float* __restrict__ b1, const float* __restrict__ W2,
    const float* __restrict__ b2, const float* __restrict__ W3,
    const float* __restrict__ ww, const float* __restrict__ wb,
    const float* __restrict__ b3,
    uint16_t* __restrict__ dxp, uint16_t* __restrict__ W1b,
    uint16_t* __restrict__ W2b, uint16_t* __restrict__ h1,
    float* __restrict__ wide, float* __restrict__ out)
{
    namespace cg = cooperative_groups;
    cg::grid_group grid = cg::this_grid();

    __shared__ __align__(16) uint16_t Al[2][4096];
    __shared__ __align__(16) uint16_t Bl[2][8192];

    const int id = blockIdx.x;       // 0..255
    const int tid = threadIdx.x;
    const int gt = id * 512 + tid;   // 0 .. 131071

    // ---------------- phase 0: prep ----------------
    for (int idx = gt; idx < 458752; idx += 131072) {   // deep_x, 16384 x 28
        int b = idx / 28, c0 = (idx - b * 28) * 8;
        u16x8 o;
        if (c0 < 192) {
            int f = c0 >> 6, cc = c0 & 63;
            int s = sp[b * 3 + f];
            const float* e = emb + (size_t)(((f << 8) + s) * 64 + cc);
            float4 v0 = *(const float4*)e;
            float4 v1 = *(const float4*)(e + 4);
            o[0] = f2bf(v0.x); o[1] = f2bf(v0.y); o[2] = f2bf(v0.z); o[3] = f2bf(v0.w);
            o[4] = f2bf(v1.x); o[5] = f2bf(v1.y); o[6] = f2bf(v1.z); o[7] = f2bf(v1.w);
        } else {
#pragma unroll
            for (int t = 0; t < 8; t++) {
                int c = c0 + t;
                o[t] = (c < DEEP_IN) ? f2bf(dense[b * 13 + (c - 192)])
                                     : (uint16_t)0;
            }
        }
        *(u16x8*)(dxp + (size_t)b * K1 + c0) = o;
    }
    if (gt < 28672) {                // W1 convert 205 -> 224
        int n = gt / 28, c0 = (gt - n * 28) * 8;
        u16x8 o;
#pragma unroll
        for (int t = 0; t < 8; t++) {
            int c = c0 + t;
            o[t] = (c < DEEP_IN) ? f2bf(W1[n * DEEP_IN + c]) : (uint16_t)0;
        }
        *(u16x8*)(W1b + (size_t)n * K1 + c0) = o;
    }
    {                                // W2 convert: exactly one vec8/thread
        const float* src = W2 + (size_t)gt * 8;
        float4 v0 = *(const float4*)src;
        float4 v1 = *(const float4*)(src + 4);
        u16x8 o;
        o[0] = f2bf(v0.x); o[1] = f2bf(v0.y); o[2] = f2bf(v0.z); o[3] = f2bf(v0.w);
        o[4] = f2bf(v1.x); o[5] = f2bf(v1.y); o[6] = f2bf(v1.z); o[7] = f2bf(v1.w);
        *(u16x8*)(W2b + (size_t)gt * 8) = o;
    }
    if (gt < BATCH) {                // wide path + b3 seed
        int b = gt;
        int s0 = sp[b * 3], s1 = sp[b * 3 + 1], s2 = sp[b * 3 + 2];
        float w = wb[0] + b3[0];
        w += ww[s0] + ww[256 + s1] + ww[512 + s2];
        w += ww[768    + s0 * 3 + s1];
        w += ww[66304  + s0 * 3 + s2];
        w += ww[131840 + s1 * 3 + s2];
        w += ww[197376 + (s0 * 3 + s1) * 3 + s2];
        const float* wd = ww + 16974592;
        float a2 = 0.f;
#pragma unroll
        for (int j = 0; j < 13; j++) a2 += dense[b * 13 + j] * wd[j];
        wide[b] = w + a2;
    }

    grid.sync();

    // ---------------- phase 1: GEMM1 -> h1 (2 tiles/block) ----------------
#pragma unroll 1
    for (int t = 0; t < 2; ++t) {
        __syncthreads();
        const int M = BATCH;
        GEMM_CORE(dxp, W1b, K1, id + t * 256)
        float bv[4];
#pragma unroll
        for (int j = 0; j < 4; j++) bv[j] = b1[bn + wn * 64 + 4 * rl + j];
#pragma unroll
        for (int i = 0; i < 4; i++) {
#pragma unroll
            for (int r = 0; r < 4; r++) {
                int m = bm + wm * 64 + i * 16 + q * 4 + r;
                u16x4 o;
#pragma unroll
                for (int j = 0; j < 4; j++)
                    o[j] = f2bf(fmaxf(acc[i][j][r] + bv[j], 0.f));
                *(u16x4*)&h1[(size_t)m * HDIM + bn + wn * 64 + 4 * rl] = o;
            }
        }
    }

    grid.sync();

    // ---------------- phase 2: GEMM2 + W3 fold (2 tiles/block) ------------
#pragma unroll 1
    for (int t = 0; t < 2; ++t) {
        __syncthreads();
        const int M = BATCH;
        GEMM_CORE(h1, W2b, HDIM, id + t * 256)
        float bv[4], w3v[4];
#pragma unroll
        for (int j = 0; j < 4; j++) {
            int n = bn + wn * 64 + 4 * rl + j;
            bv[j] = b2[n];
            w3v[j] = W3[n];
        }
#pragma unroll
        for (int i = 0; i < 4; i++) {
#pragma unroll
            for (int r = 0; r < 4; r++) {
                float pt = 0.f;
#pragma unroll
                for (int j = 0; j < 4; j++)
                    pt += fmaxf(acc[i][j][r] + bv[j], 0.f) * w3v[j];
                pt += __shfl_xor(pt, 1);
                pt += __shfl_xor(pt, 2);
                pt += __shfl_xor(pt, 4);
                pt += __shfl_xor(pt, 8);
                if (rl == 0) {
                    int m = bm + wm * 64 + i * 16 + q * 4 + r;
                    atomicAdd(&wide[m], pt);
                }
            }
        }
    }

    grid.sync();

    // ---------------- phase 3: sigmoid ----------------
    if (gt < BATCH) out[gt] = 1.f / (1.f + __expf(-wide[gt]));
}

// ===========================================================================
// Fallback path: R12 4-kernel pipeline (proven 181.9 us).
// ===========================================================================
__global__ __launch_bounds__(256) void prep_kernel(
    const int* __restrict__ sp, const float* __restrict__ dense,
    const float* __restrict__ emb, const float* __restrict__ W1,
    uint16_t* __restrict__ dx, uint16_t* __restrict__ W1b)
{
    const int bid = blockIdx.x;
    if (bid < 1792) {
        int idx = bid * 256 + threadIdx.x;
        int b = idx / 28, c0 = (idx - b * 28) * 8;
        u16x8 o;
        if (c0 < 192) {
            int f = c0 >> 6, cc = c0 & 63;
            int s = sp[b * 3 + f];
            const float* e = emb + (size_t)(((f << 8) + s) * 64 + cc);
            float4 v0 = *(const float4*)e;
            float4 v1 = *(const float4*)(e + 4);
            o[0] = f2bf(v0.x); o[1] = f2bf(v0.y); o[2] = f2bf(v0.z); o[3] = f2bf(v0.w);
            o[4] = f2bf(v1.x); o[5] = f2bf(v1.y); o[6] = f2bf(v1.z); o[7] = f2bf(v1.w);
        } else {
#pragma unroll
            for (int t = 0; t < 8; t++) {
                int c = c0 + t;
                o[t] = (c < DEEP_IN) ? f2bf(dense[b * 13 + (c - 192)])
                                     : (uint16_t)0;
            }
        }
        *(u16x8*)(dx + (size_t)b * K1 + c0) = o;
    } else {
        int idx = (bid - 1792) * 256 + threadIdx.x;
        int n = idx / 28, c0 = (idx - n * 28) * 8;
        u16x8 o;
#pragma unroll
        for (int t = 0; t < 8; t++) {
            int c = c0 + t;
            o[t] = (c < DEEP_IN) ? f2bf(W1[n * DEEP_IN + c]) : (uint16_t)0;
        }
        *(u16x8*)(W1b + (size_t)n * K1 + c0) = o;
    }
}

__global__ __launch_bounds__(512, 4) void gemm_relu(
    const uint16_t* __restrict__ A, const uint16_t* __restrict__ Bw,
    const float* __restrict__ bias, uint16_t* __restrict__ C,
    const float* __restrict__ W2, uint16_t* __restrict__ W2b,
    const int* __restrict__ sp, const float* __restrict__ dense,
    const float* __restrict__ ww, const float* __restrict__ wb,
    const float* __restrict__ b3, float* __restrict__ wide,
    int M, int N, int K)
{
    const int id = blockIdx.x;
    const int tid = threadIdx.x;

    if (id >= 512) {
        if (id < 768) {
            int k = (id - 512) * 512 + tid;
            const float* src = W2 + (size_t)k * 8;
            float4 v0 = *(const float4*)src;
            float4 v1 = *(const float4*)(src + 4);
            u16x8 o;
            o[0] = f2bf(v0.x); o[1] = f2bf(v0.y); o[2] = f2bf(v0.z); o[3] = f2bf(v0.w);
            o[4] = f2bf(v1.x); o[5] = f2bf(v1.y); o[6] = f2bf(v1.z); o[7] = f2bf(v1.w);
            *(u16x8*)(W2b + (size_t)k * 8) = o;
        } else {
            int b = (id - 768) * 512 + tid;
            int s0 = sp[b * 3], s1 = sp[b * 3 + 1], s2 = sp[b * 3 + 2];
            float w = wb[0] + b3[0];
            w += ww[s0] + ww[256 + s1] + ww[512 + s2];
            w += ww[768    + s0 * 3 + s1];
            w += ww[66304  + s0 * 3 + s2];
            w += ww[131840 + s1 * 3 + s2];
            w += ww[197376 + (s0 * 3 + s1) * 3 + s2];
            const float* wd = ww + 16974592;
            float acc2 = 0.f;
#pragma unroll
            for (int j = 0; j < 13; j++) acc2 += dense[b * 13 + j] * wd[j];
            wide[b] = w + acc2;
        }
        return;
    }

    __shared__ __align__(16) uint16_t Al[2][4096];
    __shared__ __align__(16) uint16_t Bl[2][8192];
    GEMM_CORE(A, Bw, K, id)
    float bv[4];
#pragma unroll
    for (int j = 0; j < 4; j++) bv[j] = bias[bn + wn * 64 + 4 * rl + j];
#pragma unroll
    for (int i = 0; i < 4; i++) {
#pragma unroll
        for (int r = 0; r < 4; r++) {
            int m = bm + wm * 64 + i * 16 + q * 4 + r;
            u16x4 o;
#pragma unroll
            for (int j = 0; j < 4; j++)
                o[j] = f2bf(fmaxf(acc[i][j][r] + bv[j], 0.f));
            *(u16x4*)&C[(size_t)m * N + bn + wn * 64 + 4 * rl] = o;
        }
    }
}

__global__ __launch_bounds__(512, 4) void gemm_fused(
    const uint16_t* __restrict__ A, const uint16_t* __restrict__ Bw,
    const float* __restrict__ bias, const float* __restrict__ W3,
    float* __restrict__ outacc, int M, int N, int K)
{
    const int id = blockIdx.x;
    const int tid = threadIdx.x;
    __shared__ __align__(16) uint16_t Al[2][4096];
    __shared__ __align__(16) uint16_t Bl[2][8192];
    GEMM_CORE(A, Bw, K, id)
    float bv[4], w3v[4];
#pragma unroll
    for (int j = 0; j < 4; j++) {
        int n = bn + wn * 64 + 4 * rl + j;
        bv[j] = bias[n];
        w3v[j] = W3[n];
    }
#pragma unroll
    for (int i = 0; i < 4; i++) {
#pragma unroll
        for (int r = 0; r < 4; r++) {
            float pt = 0.f;
#pragma unroll
            for (int j = 0; j < 4; j++)
                pt += fmaxf(acc[i][j][r] + bv[j], 0.f) * w3v[j];
            pt += __shfl_xor(pt, 1);
            pt += __shfl_xor(pt, 2);
            pt += __shfl_xor(pt, 4);
            pt += __shfl_xor(pt, 8);
            if (rl == 0) {
                int m = bm + wm * 64 + i * 16 + q * 4 + r;
                atomicAdd(&outacc[m], pt);
            }
        }
    }
}

__global__ __launch_bounds__(256) void sigmoid_kernel(
    const float* __restrict__ outacc, float* __restrict__ out)
{
    int b = blockIdx.x * 256 + threadIdx.x;
    out[b] = 1.f / (1.f + __expf(-outacc[b]));
}

// ---------------------------------------------------------------------------
extern "C" void kernel_launch(void* const* d_in, const int* in_sizes, int n_in,
                              void* d_out, int out_size, void* d_ws, size_t ws_size,
                              hipStream_t stream) {
    const int*   sp    = (const int*)d_in[0];
    const float* dense = (const float*)d_in[1];
    const float* ww    = (const float*)d_in[2];
    const float* wb    = (const float*)d_in[3];
    const float* emb   = (const float*)d_in[4];
    const float* W1    = (const float*)d_in[5];
    const float* b1    = (const float*)d_in[6];
    const float* W2    = (const float*)d_in[7];
    const float* b2    = (const float*)d_in[8];
    const float* W3    = (const float*)d_in[9];
    const float* b3    = (const float*)d_in[10];
    float* out = (float*)d_out;

    char* ws = (char*)d_ws;
    float*    wide = (float*)ws;                       //     65,536 B
    uint16_t* dxp  = (uint16_t*)(ws + 65536);          //  7,340,032 B (16384x224)
    uint16_t* W1b  = (uint16_t*)(ws + 7405568);        //    458,752 B (1024x224)
    uint16_t* W2b  = (uint16_t*)(ws + 7864320);        //  2,097,152 B
    uint16_t* h1   = (uint16_t*)(ws + 9961472);        // 33,554,432 B -> 43,515,904 total

    void* args[] = {
        (void*)&sp, (void*)&dense, (void*)&emb, (void*)&W1, (void*)&b1,
        (void*)&W2, (void*)&b2, (void*)&W3, (void*)&ww, (void*)&wb,
        (void*)&b3, (void*)&dxp, (void*)&W1b, (void*)&W2b, (void*)&h1,
        (void*)&wide, (void*)&out
    };
    hipError_t err = hipLaunchCooperativeKernel(
        (const void*)wad_mega, dim3(256), dim3(512), args, 0, stream);

    if (err != hipSuccess) {
        // Deterministic fallback: R12 pipeline.
        prep_kernel<<<1904, 256, 0, stream>>>(sp, dense, emb, W1, dxp, W1b);
        gemm_relu<<<800, 512, 0, stream>>>(
            dxp, W1b, b1, h1, W2, W2b, sp, dense, ww, wb, b3, wide,
            BATCH, HDIM, K1);
        gemm_fused<<<(BATCH / 128) * 4, 512, 0, stream>>>(
            h1, W2b, b2, W3, wide, BATCH, HDIM, HDIM);
        sigmoid_kernel<<<BATCH / 256, 256, 0, stream>>>(wide, out);
    }
}

// Round 15
// 181.436 us; speedup vs baseline: 1.9239x; 1.9239x over previous
//
#include <hip/hip_runtime.h>
#include <stdint.h>

// ---------------------------------------------------------------------------
// WideAndDeep: B=16384, F=3, C=256, D=64, H=1024, ND=13
// deep_in = 205 padded to 224 (7 x BK=32).
// BEST MEASURED CONFIG (R12, 181.9 us). Session findings:
//  - GEMM core plateau 54.4-57.8 us across 7 structural variants; this
//    (BK=32 dbuf, 128x256, 2 blocks/CU, 16x16x32 MFMA) is the best.
//  - ~100 us of total is FIXED harness overhead (proven by R14's
//    single-cooperative-dispatch: residual persisted at ~127 us).
//  - grid.sync()/device-scope fences cause XCD L2 writeback storms (R8/R14).
// GEMM core: 128x256 tile, 8 waves 2m x 4n, wave tile 64x64, 16x16x32 MFMA,
// BK=32 dbuf LDS, global_load_lds(16B), permuted B-cols (frag j = col 4rl+j)
// so epilogue stores are u16x4-packed full-width row transactions.
// gemm_fused folds relu(acc+b2).W3 -> atomicAdd(wide). No device fences.
// ---------------------------------------------------------------------------

#define BATCH 16384
#define HDIM 1024
#define K1 224
#define DEEP_IN 205

typedef short bf16x8 __attribute__((ext_vector_type(8)));
typedef float f32x4 __attribute__((ext_vector_type(4)));
typedef uint16_t u16x8 __attribute__((ext_vector_type(8)));
typedef uint16_t u16x4 __attribute__((ext_vector_type(4)));

__device__ __forceinline__ uint16_t f2bf(float f) {
    uint32_t x;
    __builtin_memcpy(&x, &f, 4);
    uint32_t r = (x + 0x7fffu + ((x >> 16) & 1u)) >> 16;
    return (uint16_t)r;
}

__device__ __forceinline__ void async_ld16(const uint16_t* g, uint16_t* l) {
    __builtin_amdgcn_global_load_lds(
        (const __attribute__((address_space(1))) uint32_t*)g,
        (__attribute__((address_space(3))) uint32_t*)l, 16, 0, 0);
}

// ---------------------------------------------------------------------------
// prep: only what gemm_relu needs.
//   [0, 1792)     : build deep_x [B][224] bf16 (x8 vectorized)
//   [1792, 1904)  : W1 -> bf16, 205 -> 224 K-pad (x8)
// ---------------------------------------------------------------------------
__global__ __launch_bounds__(256) void prep_kernel(
    const int* __restrict__ sp, const float* __restrict__ dense,
    const float* __restrict__ emb, const float* __restrict__ W1,
    uint16_t* __restrict__ dx, uint16_t* __restrict__ W1b)
{
    const int bid = blockIdx.x;
    if (bid < 1792) {                      // ---- deep_x build (16384 x 28 vec8)
        int idx = bid * 256 + threadIdx.x; // < 458752
        int b = idx / 28, c0 = (idx - b * 28) * 8;
        u16x8 o;
        if (c0 < 192) {
            int f = c0 >> 6, cc = c0 & 63;
            int s = sp[b * 3 + f];
            const float* e = emb + (size_t)(((f << 8) + s) * 64 + cc);
            float4 v0 = *(const float4*)e;
            float4 v1 = *(const float4*)(e + 4);
            o[0] = f2bf(v0.x); o[1] = f2bf(v0.y); o[2] = f2bf(v0.z); o[3] = f2bf(v0.w);
            o[4] = f2bf(v1.x); o[5] = f2bf(v1.y); o[6] = f2bf(v1.z); o[7] = f2bf(v1.w);
        } else {
#pragma unroll
            for (int t = 0; t < 8; t++) {
                int c = c0 + t;
                o[t] = (c < DEEP_IN) ? f2bf(dense[b * 13 + (c - 192)])
                                     : (uint16_t)0;
            }
        }
        *(u16x8*)(dx + (size_t)b * K1 + c0) = o;
    } else {                               // ---- W1 convert, 205 -> 224
        int idx = (bid - 1792) * 256 + threadIdx.x;  // < 28672
        int n = idx / 28, c0 = (idx - n * 28) * 8;
        u16x8 o;
#pragma unroll
        for (int t = 0; t < 8; t++) {
            int c = c0 + t;
            o[t] = (c < DEEP_IN) ? f2bf(W1[n * DEEP_IN + c]) : (uint16_t)0;
        }
        *(u16x8*)(W1b + (size_t)n * K1 + c0) = o;
    }
}

// ---------------------------------------------------------------------------
// Shared GEMM core (permuted B columns).
// 128x256 tile, 8 waves (wm = wave>>2, wn = wave&3), wave tile 64x64.
// A: 8 chunks, chunk w = rows bm+w*16..+16 (natural order).
// B: 16 chunks; chunk c holds cols { bn + (c>>2)*64 + 4*rl + (c&3) } so
//    compute frag j (chunk wn*4+j) gives lane (q,rl) col bn+wn*64+4rl+j.
// BK=32 double-buffered; per-iter: 3 async_ld16/wave, 8 ds_read_b128,
// 16 MFMA 16x16x32, vmcnt(0)+__syncthreads.
// Grid (M/128)*4 = 512 blocks = 2/CU; XCD swizzle groups 4 n-sharers per XCD.
// ---------------------------------------------------------------------------
#define GEMM_CORE(A_, B_, K_)                                                  \
    const int lane = tid & 63;                                                 \
    const int wave = tid >> 6;                                                 \
    const int wm = wave >> 2;                                                  \
    const int wn = wave & 3;                                                   \
    const int xcd = id & 7;                                                    \
    const int slot = id >> 3;                                                  \
    const int mbX = (M >> 7) >> 3;                                             \
    const int by = xcd * mbX + (slot >> 2);                                    \
    const int bx = slot & 3;                                                   \
    const int bm = by * 128;                                                   \
    const int bn = bx * 256;                                                   \
    const int rl = lane & 15, q = lane >> 4;                                   \
    f32x4 acc[4][4];                                                           \
    _Pragma("unroll") for (int i = 0; i < 4; i++)                              \
        _Pragma("unroll") for (int j = 0; j < 4; j++) acc[i][j] = (f32x4)0.f;  \
    const int cc0 = 2 * wave, cc1 = 2 * wave + 1;                              \
    const uint16_t* aS = A_ + (size_t)(bm + wave * 16 + rl) * K_ + q * 8;      \
    const uint16_t* bS0 = B_ + (size_t)(bn + (cc0 >> 2) * 64 + 4 * rl + (cc0 & 3)) * K_ + q * 8; \
    const uint16_t* bS1 = B_ + (size_t)(bn + (cc1 >> 2) * 64 + 4 * rl + (cc1 & 3)) * K_ + q * 8; \
    const int dA = wave * 512, dB0 = cc0 * 512, dB1 = cc1 * 512;               \
    async_ld16(aS, &Al[0][dA]);                                                \
    async_ld16(bS0, &Bl[0][dB0]);                                              \
    async_ld16(bS1, &Bl[0][dB1]);                                              \
    asm volatile("s_waitcnt vmcnt(0)" ::: "memory");                           \
    __syncthreads();                                                           \
    int p = 0;                                                                 \
    for (int k0 = 32; k0 < K_; k0 += 32) {                                     \
        async_ld16(aS + k0, &Al[p ^ 1][dA]);                                   \
        async_ld16(bS0 + k0, &Bl[p ^ 1][dB0]);                                 \
        async_ld16(bS1 + k0, &Bl[p ^ 1][dB1]);                                 \
        bf16x8 af[4], bfr[4];                                                  \
        _Pragma("unroll") for (int i = 0; i < 4; i++)                          \
            af[i] = *(const bf16x8*)&Al[p][(wm * 4 + i) * 512 + lane * 8];     \
        _Pragma("unroll") for (int j = 0; j < 4; j++)                          \
            bfr[j] = *(const bf16x8*)&Bl[p][(wn * 4 + j) * 512 + lane * 8];    \
        _Pragma("unroll") for (int i = 0; i < 4; i++)                          \
            _Pragma("unroll") for (int j = 0; j < 4; j++)                      \
                acc[i][j] = __builtin_amdgcn_mfma_f32_16x16x32_bf16(           \
                    af[i], bfr[j], acc[i][j], 0, 0, 0);                        \
        asm volatile("s_waitcnt vmcnt(0)" ::: "memory");                       \
        __syncthreads();                                                       \
        p ^= 1;                                                                \
    }                                                                          \
    {                                                                          \
        bf16x8 af[4], bfr[4];                                                  \
        _Pragma("unroll") for (int i = 0; i < 4; i++)                          \
            af[i] = *(const bf16x8*)&Al[p][(wm * 4 + i) * 512 + lane * 8];     \
        _Pragma("unroll") for (int j = 0; j < 4; j++)                          \
            bfr[j] = *(const bf16x8*)&Bl[p][(wn * 4 + j) * 512 + lane * 8];    \
        _Pragma("unroll") for (int i = 0; i < 4; i++)                          \
            _Pragma("unroll") for (int j = 0; j < 4; j++)                      \
                acc[i][j] = __builtin_amdgcn_mfma_f32_16x16x32_bf16(           \
                    af[i], bfr[j], acc[i][j], 0, 0, 0);                        \
    }

// ---------------------------------------------------------------------------
// gemm_relu: [0,512) h1 = relu(dxp @ W1b^T + b1), u16x4 packed row stores;
//            [512,768) W2 -> bf16 convert; [768,800) wide path + b3 seed.
// ---------------------------------------------------------------------------
__global__ __launch_bounds__(512, 4) void gemm_relu(
    const uint16_t* __restrict__ A, const uint16_t* __restrict__ Bw,
    const float* __restrict__ bias, uint16_t* __restrict__ C,
    const float* __restrict__ W2, uint16_t* __restrict__ W2b,
    const int* __restrict__ sp, const float* __restrict__ dense,
    const float* __restrict__ ww, const float* __restrict__ wb,
    const float* __restrict__ b3, float* __restrict__ wide,
    int M, int N, int K)
{
    const int id = blockIdx.x;
    const int tid = threadIdx.x;

    if (id >= 512) {
        if (id < 768) {                    // ---- W2 convert (x8)
            int k = (id - 512) * 512 + tid;    // < 131072
            const float* src = W2 + (size_t)k * 8;
            float4 v0 = *(const float4*)src;
            float4 v1 = *(const float4*)(src + 4);
            u16x8 o;
            o[0] = f2bf(v0.x); o[1] = f2bf(v0.y); o[2] = f2bf(v0.z); o[3] = f2bf(v0.w);
            o[4] = f2bf(v1.x); o[5] = f2bf(v1.y); o[6] = f2bf(v1.z); o[7] = f2bf(v1.w);
            *(u16x8*)(W2b + (size_t)k * 8) = o;
        } else {                           // ---- wide path (+ b3 seed)
            int b = (id - 768) * 512 + tid;    // < 16384
            int s0 = sp[b * 3], s1 = sp[b * 3 + 1], s2 = sp[b * 3 + 2];
            float w = wb[0] + b3[0];
            w += ww[s0] + ww[256 + s1] + ww[512 + s2];
            w += ww[768    + s0 * 3 + s1];
            w += ww[66304  + s0 * 3 + s2];
            w += ww[131840 + s1 * 3 + s2];
            w += ww[197376 + (s0 * 3 + s1) * 3 + s2];
            const float* wd = ww + 16974592;
            float acc2 = 0.f;
#pragma unroll
            for (int j = 0; j < 13; j++) acc2 += dense[b * 13 + j] * wd[j];
            wide[b] = w + acc2;
        }
        return;
    }

    __shared__ __align__(16) uint16_t Al[2][4096];   // 128 x 32 dbuf
    __shared__ __align__(16) uint16_t Bl[2][8192];   // 256 x 32 dbuf
    GEMM_CORE(A, Bw, K)

    // Epilogue: lane (q,rl) owns cols bn+wn*64+4rl+j (j=0..3) of rows
    // m = bm+wm*64+i*16+q*4+r -> one u16x4 (8 B) store per (i,r).
    float bv[4];
#pragma unroll
    for (int j = 0; j < 4; j++) bv[j] = bias[bn + wn * 64 + 4 * rl + j];
#pragma unroll
    for (int i = 0; i < 4; i++) {
#pragma unroll
        for (int r = 0; r < 4; r++) {
            int m = bm + wm * 64 + i * 16 + q * 4 + r;
            u16x4 o;
#pragma unroll
            for (int j = 0; j < 4; j++)
                o[j] = f2bf(fmaxf(acc[i][j][r] + bv[j], 0.f));
            *(u16x4*)&C[(size_t)m * N + bn + wn * 64 + 4 * rl] = o;
        }
    }
}

// ---------------------------------------------------------------------------
// gemm_fused: per-row partial of relu(acc + b2) . W3 -> atomicAdd(outacc).
// (n-permutation is irrelevant to the sum.)
// ---------------------------------------------------------------------------
__global__ __launch_bounds__(512, 4) void gemm_fused(
    const uint16_t* __restrict__ A, const uint16_t* __restrict__ Bw,
    const float* __restrict__ bias, const float* __restrict__ W3,
    float* __restrict__ outacc, int M, int N, int K)
{
    const int id = blockIdx.x;
    const int tid = threadIdx.x;
    __shared__ __align__(16) uint16_t Al[2][4096];
    __shared__ __align__(16) uint16_t Bl[2][8192];
    GEMM_CORE(A, Bw, K)

    float bv[4], w3v[4];
#pragma unroll
    for (int j = 0; j < 4; j++) {
        int n = bn + wn * 64 + 4 * rl + j;
        bv[j] = bias[n];
        w3v[j] = W3[n];
    }
#pragma unroll
    for (int i = 0; i < 4; i++) {
#pragma unroll
        for (int r = 0; r < 4; r++) {
            float pt = 0.f;
#pragma unroll
            for (int j = 0; j < 4; j++)
                pt += fmaxf(acc[i][j][r] + bv[j], 0.f) * w3v[j];
            pt += __shfl_xor(pt, 1);
            pt += __shfl_xor(pt, 2);
            pt += __shfl_xor(pt, 4);
            pt += __shfl_xor(pt, 8);
            if (rl == 0) {
                int m = bm + wm * 64 + i * 16 + q * 4 + r;
                atomicAdd(&outacc[m], pt);
            }
        }
    }
}

// ---------------------------------------------------------------------------
// Sigmoid over the accumulated logits. Grid 64 x 256.
// ---------------------------------------------------------------------------
__global__ __launch_bounds__(256) void sigmoid_kernel(
    const float* __restrict__ outacc, float* __restrict__ out)
{
    int b = blockIdx.x * 256 + threadIdx.x;
    out[b] = 1.f / (1.f + __expf(-outacc[b]));
}

// ---------------------------------------------------------------------------
extern "C" void kernel_launch(void* const* d_in, const int* in_sizes, int n_in,
                              void* d_out, int out_size, void* d_ws, size_t ws_size,
                              hipStream_t stream) {
    const int*   sp    = (const int*)d_in[0];
    const float* dense = (const float*)d_in[1];
    const float* ww    = (const float*)d_in[2];
    const float* wb    = (const float*)d_in[3];
    const float* emb   = (const float*)d_in[4];
    const float* W1    = (const float*)d_in[5];
    const float* b1    = (const float*)d_in[6];
    const float* W2    = (const float*)d_in[7];
    const float* b2    = (const float*)d_in[8];
    const float* W3    = (const float*)d_in[9];
    const float* b3    = (const float*)d_in[10];
    float* out = (float*)d_out;

    char* ws = (char*)d_ws;
    float*    wide = (float*)ws;                       //     65,536 B
    uint16_t* dxp  = (uint16_t*)(ws + 65536);          //  7,340,032 B (16384x224)
    uint16_t* W1b  = (uint16_t*)(ws + 7405568);        //    458,752 B (1024x224)
    uint16_t* W2b  = (uint16_t*)(ws + 7864320);        //  2,097,152 B
    uint16_t* h1   = (uint16_t*)(ws + 9961472);        // 33,554,432 B -> 43,515,904 total

    prep_kernel<<<1904, 256, 0, stream>>>(sp, dense, emb, W1, dxp, W1b);
    gemm_relu<<<800, 512, 0, stream>>>(
        dxp, W1b, b1, h1, W2, W2b, sp, dense, ww, wb, b3, wide,
        BATCH, HDIM, K1);
    gemm_fused<<<(BATCH / 128) * 4, 512, 0, stream>>>(
        h1, W2b, b2, W3, wide, BATCH, HDIM, HDIM);
    sigmoid_kernel<<<BATCH / 256, 256, 0, stream>>>(wide, out);
}